// Round 8
// baseline (253.779 us; speedup 1.0000x reference)
//
#include <hip/hip_runtime.h>
#include <hip/hip_bf16.h>
#include <cstdint>

#define NN 2048
#define BB 8
#define DIN 128
#define DOUT 64

typedef __attribute__((ext_vector_type(8))) short bf16x8;
typedef __attribute__((ext_vector_type(4))) float f32x4;

static __device__ __forceinline__ unsigned short f2b(float f) {
    union { __hip_bfloat16 h; unsigned short s; } u;
    u.h = __float2bfloat16(f);
    return u.s;
}

// ---------------------------------------------------------------------------
// Kernel 1: xp = x@W^T + b via MFMA, K split across 4 waves. 32 rows/block,
// grid 512. Outputs:
//   xpF  : fragment-ordered bf16 B-operand tensor. Tile (b, dt, kb) holds the
//          16x16x32 MFMA B-frag: lane l gets xp[n = kb*32 + (l>>4)*8 + j]
//          [d = dt*16 + (l&15)], j=0..7. Attn reads it as ONE coalesced
//          dwordx4 per lane (kills the 16-row gather that survived R3-R7).
//   e_src/e_dst : rank-1 logit dots (fp32, from fp32 accumulators).
// ---------------------------------------------------------------------------
__global__ __launch_bounds__(256) void gat_xp_mfma(
    const float* __restrict__ x, const float* __restrict__ W,
    const float* __restrict__ bias, const float* __restrict__ a,
    unsigned short* __restrict__ xpF, float* __restrict__ e_src,
    float* __restrict__ e_dst)
{
    __shared__ float red[4 * 32 * 65];   // [w][row][d+pad] 33.3 KB
    const int t = threadIdx.x;
    const int lane = t & 63;
    const int w = t >> 6;
    const int lr = lane & 15;
    const int g  = lane >> 4;
    const int r0 = blockIdx.x * 32;
    const int k0 = w * 32 + g * 8;

    // W frags once (k-range of this wave, 4 d-tiles)
    bf16x8 bfr[4];
    #pragma unroll
    for (int dt = 0; dt < 4; ++dt) {
        const float* wr = W + (size_t)(dt * 16 + lr) * DIN + k0;
        const float4 wa = *(const float4*)wr;
        const float4 wb = *(const float4*)(wr + 4);
        bfr[dt][0]=f2b(wa.x); bfr[dt][1]=f2b(wa.y); bfr[dt][2]=f2b(wa.z); bfr[dt][3]=f2b(wa.w);
        bfr[dt][4]=f2b(wb.x); bfr[dt][5]=f2b(wb.y); bfr[dt][6]=f2b(wb.z); bfr[dt][7]=f2b(wb.w);
    }
    #pragma unroll
    for (int half = 0; half < 2; ++half) {
        const float* xr = x + (size_t)(r0 + half * 16 + lr) * DIN + k0;
        const float4 xa = *(const float4*)xr;
        const float4 xb4 = *(const float4*)(xr + 4);
        bf16x8 afr;
        afr[0]=f2b(xa.x);  afr[1]=f2b(xa.y);  afr[2]=f2b(xa.z);  afr[3]=f2b(xa.w);
        afr[4]=f2b(xb4.x); afr[5]=f2b(xb4.y); afr[6]=f2b(xb4.z); afr[7]=f2b(xb4.w);
        #pragma unroll
        for (int dt = 0; dt < 4; ++dt) {
            f32x4 acc = {0.f, 0.f, 0.f, 0.f};
            acc = __builtin_amdgcn_mfma_f32_16x16x32_bf16(afr, bfr[dt], acc, 0, 0, 0);
            #pragma unroll
            for (int reg = 0; reg < 4; ++reg)
                red[w * 2080 + (half * 16 + g * 4 + reg) * 65 + dt * 16 + lr] = acc[reg];
        }
    }
    __syncthreads();

    const int b  = r0 >> 11;
    const int kb = (r0 & (NN - 1)) >> 5;

    // pass 1: e_src/e_dst (thread = (row, dq); shfl reduce over the 16 dq lanes)
    #pragma unroll
    for (int i = 0; i < 2; ++i) {
        const int row = i * 16 + (t >> 4);
        const int dq  = t & 15;
        float es = 0.f, ed = 0.f;
        #pragma unroll
        for (int j = 0; j < 4; ++j) {
            const int d = dq * 4 + j;
            const float v = red[0 * 2080 + row * 65 + d] + red[1 * 2080 + row * 65 + d]
                          + red[2 * 2080 + row * 65 + d] + red[3 * 2080 + row * 65 + d]
                          + bias[d];
            es += v * a[d];
            ed += v * a[DOUT + d];
        }
        es += __shfl_xor(es, 1); es += __shfl_xor(es, 2);
        es += __shfl_xor(es, 4); es += __shfl_xor(es, 8);
        ed += __shfl_xor(ed, 1); ed += __shfl_xor(ed, 2);
        ed += __shfl_xor(ed, 4); ed += __shfl_xor(ed, 8);
        if (dq == 0) {
            e_src[r0 + row] = es;
            e_dst[r0 + row] = ed;
        }
    }

    // pass 2: fragment-ordered xpF store (wave = dt; one coalesced dwordx4/lane)
    {
        const int dt = w;
        const int d  = dt * 16 + lr;
        const float bv = bias[d];
        bf16x8 frag;
        #pragma unroll
        for (int j = 0; j < 8; ++j) {
            const int row = g * 8 + j;
            const float v = red[0 * 2080 + row * 65 + d] + red[1 * 2080 + row * 65 + d]
                          + red[2 * 2080 + row * 65 + d] + red[3 * 2080 + row * 65 + d]
                          + bv;
            frag[j] = f2b(v);
        }
        *(bf16x8*)(xpF + ((size_t)((b * 4 + dt) * 64 + kb) << 9) + lane * 8) = frag;
    }
}

// ---------------------------------------------------------------------------
// Kernel 2: fused masked-softmax + PV. Grid 1024 = (b, 16-row m-tile);
// 4 waves, wave w = output d-tile. NO LDS P, NO in-loop barriers, no asm.
// Prologue: block packs its 16 adj rows (128 KB, coalesced, read once) into
// a 4 KB LDS bitmask (nibble + 3x shfl-or); stages e_dst (8 KB) + batch max.
// Main loop (64 k-steps, barrier-free dataflow):
//   mask word (LDS b32, padded stride 65 -> banks (lr+ks)%32, conflict-free)
//   e_dst 2x b128 broadcast; p = exp(leaky(s+d)-bnd) in A-frag layout
//   B-frag = ONE coalesced 1KB wave-load from xpF; 1 MFMA into acc.
// Epilogue: shfl-only row-sums, normalize, store. Softmax shift
// bnd = leaky(s_m + dmax_b) >= row max (monotone) -> softmax-invariant.
// ---------------------------------------------------------------------------
__global__ __launch_bounds__(256) void gat_attn_mfma(
    const int* __restrict__ adj, const unsigned short* __restrict__ xpF,
    const float* __restrict__ e_src, const float* __restrict__ e_dst,
    float* __restrict__ out)
{
    __shared__ float d_lds[NN];              // 8 KB
    __shared__ unsigned int mk[16 * 65];     // 4.2 KB padded bitmask
    __shared__ float mred[4];
    __shared__ float s_lds[16];
    __shared__ float bnd_lds[16];

    const int t = threadIdx.x;
    const int lane = t & 63;
    const int w = t >> 6;
    const int lr = lane & 15;
    const int g  = lane >> 4;
    const int b  = blockIdx.x >> 7;
    const int m0 = (blockIdx.x & 127) * 16;
    const size_t base = (size_t)b * NN;

    // ---- in-block adj pack: 16 rows x 2048 = 32K ints -> 4 KB bitmask ----
    const int* __restrict__ arow = adj + ((base + m0) << 11);
    #pragma unroll 4
    for (int s = 0; s < 32; ++s) {
        const int f = s * 1024 + t * 4;
        const int4 v = *(const int4*)(arow + f);
        unsigned int wv = ((v.x != 0) ? 1u : 0u) | ((v.y != 0) ? 2u : 0u)
                        | ((v.z != 0) ? 4u : 0u) | ((v.w != 0) ? 8u : 0u);
        wv <<= ((t & 7) * 4);
        wv |= __shfl_xor(wv, 1);
        wv |= __shfl_xor(wv, 2);
        wv |= __shfl_xor(wv, 4);
        if ((t & 7) == 0)
            mk[(f >> 11) * 65 + ((f & (NN - 1)) >> 5)] = wv;
    }

    // ---- stage e_dst + per-batch max ----
    float dm = -1e30f;
    #pragma unroll
    for (int i = 0; i < 8; ++i) {
        const float v = e_dst[base + i * 256 + t];
        d_lds[i * 256 + t] = v;
        dm = fmaxf(dm, v);
    }
    #pragma unroll
    for (int off = 32; off >= 1; off >>= 1) dm = fmaxf(dm, __shfl_xor(dm, off));
    if (lane == 0) mred[w] = dm;
    __syncthreads();
    const float dmax = fmaxf(fmaxf(mred[0], mred[1]), fmaxf(mred[2], mred[3]));
    if (t < 16) {
        const float s = e_src[base + m0 + t];
        const float e0 = s + dmax;
        s_lds[t] = s;
        bnd_lds[t] = fmaxf(e0, 0.2f * e0);
    }
    __syncthreads();

    const float sreg = s_lds[lr];     // this lane's P-row (A-frag row = lr)
    const float bnd  = bnd_lds[lr];

    f32x4 acc = {0.f, 0.f, 0.f, 0.f};
    float rs = 0.f;
    const unsigned short* __restrict__ xv =
        xpF + ((size_t)((b * 4 + w) * 64) << 9) + lane * 8;

    #pragma unroll 8
    for (int ks = 0; ks < 64; ++ks) {
        const unsigned int mw = mk[lr * 65 + ks];
        const float4 d0 = *(const float4*)(d_lds + ks * 32 + g * 8);
        const float4 d1 = *(const float4*)(d_lds + ks * 32 + g * 8 + 4);
        const float dvv[8] = {d0.x, d0.y, d0.z, d0.w, d1.x, d1.y, d1.z, d1.w};
        bf16x8 afr;
        #pragma unroll
        for (int j = 0; j < 8; ++j) {
            const float e = sreg + dvv[j];
            const float le = fmaxf(e, 0.2f * e);
            const float pe = __expf(le - bnd);
            const float p = ((mw >> (g * 8 + j)) & 1u) ? pe : 0.f;
            rs += p;
            afr[j] = f2b(p);
        }
        const bf16x8 bfr = *(const bf16x8*)(xv + (size_t)ks * 512);
        acc = __builtin_amdgcn_mfma_f32_16x16x32_bf16(afr, bfr, acc, 0, 0, 0);
    }

    // ---- row sums: reduce over the 4 g-copies of each row (shfl-only) ----
    rs += __shfl_xor(rs, 16);
    rs += __shfl_xor(rs, 32);   // now every lane holds rowsum(its lr)

    #pragma unroll
    for (int reg = 0; reg < 4; ++reg) {
        const int row = g * 4 + reg;                 // C-frag row (m89 layout)
        const float nrm = __shfl(rs, row);           // rowsum(row) from lane 'row'
        out[(base + (size_t)(m0 + row)) * DOUT + w * 16 + lr] = acc[reg] / nrm;
    }
}

extern "C" void kernel_launch(void* const* d_in, const int* in_sizes, int n_in,
                              void* d_out, int out_size, void* d_ws, size_t ws_size,
                              hipStream_t stream) {
    const float* x    = (const float*)d_in[0];
    const int*   adj  = (const int*)d_in[1];
    const float* W    = (const float*)d_in[2];
    const float* bvec = (const float*)d_in[3];
    const float* a    = (const float*)d_in[4];
    float* out = (float*)d_out;

    unsigned short* xpF = (unsigned short*)d_ws;          // 2 MB bf16 frag-ordered
    float* e_src = (float*)((char*)d_ws + (1 << 21));     // 64 KB
    float* e_dst = e_src + (size_t)BB * NN;               // 64 KB

    gat_xp_mfma<<<(BB * NN) / 32, 256, 0, stream>>>(x, W, bvec, a, xpF, e_src, e_dst);
    gat_attn_mfma<<<BB * (NN / 16), 256, 0, stream>>>(adj, xpF, e_src, e_dst, out);
}

// Round 9
// 225.156 us; speedup vs baseline: 1.1271x; 1.1271x over previous
//
#include <hip/hip_runtime.h>
#include <hip/hip_bf16.h>
#include <cstdint>

#define NN 2048
#define BB 8
#define DIN 128
#define DOUT 64

typedef __attribute__((ext_vector_type(8))) short bf16x8;
typedef __attribute__((ext_vector_type(4))) float f32x4;

static __device__ __forceinline__ unsigned short f2b(float f) {
    union { __hip_bfloat16 h; unsigned short s; } u;
    u.h = __float2bfloat16(f);
    return u.s;
}

// ---------------------------------------------------------------------------
// Kernel 1: xp = x@W^T + b via MFMA, K split across 4 waves. 32 rows/block,
// grid 512. Outputs:
//   xpF  : fragment-ordered bf16 B-operand tensor. Tile (b, dt, kb) holds the
//          16x16x32 MFMA B-frag: lane l gets xp[n = kb*32 + (l>>4)*8 + j]
//          [d = dt*16 + (l&15)], j=0..7. Attn reads it as ONE coalesced
//          dwordx4 per lane.
//   e_src/e_dst : rank-1 logit dots (fp32, from fp32 accumulators).
// ---------------------------------------------------------------------------
__global__ __launch_bounds__(256) void gat_xp_mfma(
    const float* __restrict__ x, const float* __restrict__ W,
    const float* __restrict__ bias, const float* __restrict__ a,
    unsigned short* __restrict__ xpF, float* __restrict__ e_src,
    float* __restrict__ e_dst)
{
    __shared__ float red[4 * 32 * 65];   // [w][row][d+pad] 33.3 KB
    const int t = threadIdx.x;
    const int lane = t & 63;
    const int w = t >> 6;
    const int lr = lane & 15;
    const int g  = lane >> 4;
    const int r0 = blockIdx.x * 32;
    const int k0 = w * 32 + g * 8;

    // W frags once (k-range of this wave, 4 d-tiles)
    bf16x8 bfr[4];
    #pragma unroll
    for (int dt = 0; dt < 4; ++dt) {
        const float* wr = W + (size_t)(dt * 16 + lr) * DIN + k0;
        const float4 wa = *(const float4*)wr;
        const float4 wb = *(const float4*)(wr + 4);
        bfr[dt][0]=f2b(wa.x); bfr[dt][1]=f2b(wa.y); bfr[dt][2]=f2b(wa.z); bfr[dt][3]=f2b(wa.w);
        bfr[dt][4]=f2b(wb.x); bfr[dt][5]=f2b(wb.y); bfr[dt][6]=f2b(wb.z); bfr[dt][7]=f2b(wb.w);
    }
    #pragma unroll
    for (int half = 0; half < 2; ++half) {
        const float* xr = x + (size_t)(r0 + half * 16 + lr) * DIN + k0;
        const float4 xa = *(const float4*)xr;
        const float4 xb4 = *(const float4*)(xr + 4);
        bf16x8 afr;
        afr[0]=f2b(xa.x);  afr[1]=f2b(xa.y);  afr[2]=f2b(xa.z);  afr[3]=f2b(xa.w);
        afr[4]=f2b(xb4.x); afr[5]=f2b(xb4.y); afr[6]=f2b(xb4.z); afr[7]=f2b(xb4.w);
        #pragma unroll
        for (int dt = 0; dt < 4; ++dt) {
            f32x4 acc = {0.f, 0.f, 0.f, 0.f};
            acc = __builtin_amdgcn_mfma_f32_16x16x32_bf16(afr, bfr[dt], acc, 0, 0, 0);
            #pragma unroll
            for (int reg = 0; reg < 4; ++reg)
                red[w * 2080 + (half * 16 + g * 4 + reg) * 65 + dt * 16 + lr] = acc[reg];
        }
    }
    __syncthreads();

    const int b  = r0 >> 11;
    const int kb = (r0 & (NN - 1)) >> 5;

    // pass 1: e_src/e_dst (thread = (row, dq); shfl reduce over the 16 dq lanes)
    #pragma unroll
    for (int i = 0; i < 2; ++i) {
        const int row = i * 16 + (t >> 4);
        const int dq  = t & 15;
        float es = 0.f, ed = 0.f;
        #pragma unroll
        for (int j = 0; j < 4; ++j) {
            const int d = dq * 4 + j;
            const float v = red[0 * 2080 + row * 65 + d] + red[1 * 2080 + row * 65 + d]
                          + red[2 * 2080 + row * 65 + d] + red[3 * 2080 + row * 65 + d]
                          + bias[d];
            es += v * a[d];
            ed += v * a[DOUT + d];
        }
        es += __shfl_xor(es, 1); es += __shfl_xor(es, 2);
        es += __shfl_xor(es, 4); es += __shfl_xor(es, 8);
        ed += __shfl_xor(ed, 1); ed += __shfl_xor(ed, 2);
        ed += __shfl_xor(ed, 4); ed += __shfl_xor(ed, 8);
        if (dq == 0) {
            e_src[r0 + row] = es;
            e_dst[r0 + row] = ed;
        }
    }

    // pass 2: fragment-ordered xpF store (wave = dt; one coalesced dwordx4/lane)
    {
        const int dt = w;
        const int d  = dt * 16 + lr;
        const float bv = bias[d];
        bf16x8 frag;
        #pragma unroll
        for (int j = 0; j < 8; ++j) {
            const int row = g * 8 + j;
            const float v = red[0 * 2080 + row * 65 + d] + red[1 * 2080 + row * 65 + d]
                          + red[2 * 2080 + row * 65 + d] + red[3 * 2080 + row * 65 + d]
                          + bv;
            frag[j] = f2b(v);
        }
        *(bf16x8*)(xpF + ((size_t)((b * 4 + dt) * 64 + kb) << 9) + lane * 8) = frag;
    }
}

// ---------------------------------------------------------------------------
// Kernel 2: fused masked-softmax + PV. Grid 1024 = (b, 16-row m-tile);
// 4 waves. R9 change vs R8: wave = K-QUARTER (not d-tile), so the P tile is
// computed ONCE per block instead of 4x (R8 counters: VALUBusy 41% = 44 us,
// 4x redundant exp/mask/cvt). Each wave: 16 k-blocks; per k-block one p-gen
// (8 elems/lane in A-frag layout) feeding 4 MFMAs (all d-tiles), acc[4].
// Epilogue: one sync; cross-wave C reduce via padded LDS + shfl row-sums.
// Main loop stays barrier-free: mask bit from LDS bitmask (padded, conflict-
// free), e_dst b128 broadcasts, ONE coalesced 1KB wave-load per B-frag.
// ---------------------------------------------------------------------------
__global__ __launch_bounds__(256) void gat_attn_mfma(
    const int* __restrict__ adj, const unsigned short* __restrict__ xpF,
    const float* __restrict__ e_src, const float* __restrict__ e_dst,
    float* __restrict__ out)
{
    __shared__ float d_lds[NN];              // 8 KB
    __shared__ unsigned int mk[16 * 65];     // 4.2 KB padded bitmask
    __shared__ float red[4][4][16][17];      // 17.4 KB [w][dt][row][col+pad]
    __shared__ float rs_lds[4 * 16];
    __shared__ float mred[4];
    __shared__ float s_lds[16];
    __shared__ float bnd_lds[16];

    const int t = threadIdx.x;
    const int lane = t & 63;
    const int w = t >> 6;
    const int lr = lane & 15;
    const int g  = lane >> 4;
    const int b  = blockIdx.x >> 7;
    const int m0 = (blockIdx.x & 127) * 16;
    const size_t base = (size_t)b * NN;

    // ---- in-block adj pack: 16 rows x 2048 = 32K ints -> 4 KB bitmask ----
    const int* __restrict__ arow = adj + ((base + m0) << 11);
    #pragma unroll 4
    for (int s = 0; s < 32; ++s) {
        const int f = s * 1024 + t * 4;
        const int4 v = *(const int4*)(arow + f);
        unsigned int wv = ((v.x != 0) ? 1u : 0u) | ((v.y != 0) ? 2u : 0u)
                        | ((v.z != 0) ? 4u : 0u) | ((v.w != 0) ? 8u : 0u);
        wv <<= ((t & 7) * 4);
        wv |= __shfl_xor(wv, 1);
        wv |= __shfl_xor(wv, 2);
        wv |= __shfl_xor(wv, 4);
        if ((t & 7) == 0)
            mk[(f >> 11) * 65 + ((f & (NN - 1)) >> 5)] = wv;
    }

    // ---- stage e_dst + per-batch max ----
    float dm = -1e30f;
    #pragma unroll
    for (int i = 0; i < 8; ++i) {
        const float v = e_dst[base + i * 256 + t];
        d_lds[i * 256 + t] = v;
        dm = fmaxf(dm, v);
    }
    #pragma unroll
    for (int off = 32; off >= 1; off >>= 1) dm = fmaxf(dm, __shfl_xor(dm, off));
    if (lane == 0) mred[w] = dm;
    __syncthreads();
    const float dmax = fmaxf(fmaxf(mred[0], mred[1]), fmaxf(mred[2], mred[3]));
    if (t < 16) {
        const float s = e_src[base + m0 + t];
        const float e0 = s + dmax;
        s_lds[t] = s;
        bnd_lds[t] = fmaxf(e0, 0.2f * e0);   // leaky(s+dmax) >= row max
    }
    __syncthreads();

    const float sreg = s_lds[lr];     // this lane's P-row (A-frag row = lr)
    const float bnd  = bnd_lds[lr];

    f32x4 acc[4] = {};
    float rs = 0.f;
    const unsigned short* __restrict__ xbase = xpF + ((size_t)(b * 4) << 15);
    const int kk0 = w * 16;           // this wave's k-quarter

    #pragma unroll 4
    for (int ks = 0; ks < 16; ++ks) {
        const int kk = kk0 + ks;
        const unsigned int mw = mk[lr * 65 + kk];
        const float4 d0 = *(const float4*)(d_lds + kk * 32 + g * 8);
        const float4 d1 = *(const float4*)(d_lds + kk * 32 + g * 8 + 4);
        const float dvv[8] = {d0.x, d0.y, d0.z, d0.w, d1.x, d1.y, d1.z, d1.w};
        bf16x8 afr;
        #pragma unroll
        for (int j = 0; j < 8; ++j) {
            const float e = sreg + dvv[j];
            const float le = fmaxf(e, 0.2f * e);
            const float pe = __expf(le - bnd);
            const float p = ((mw >> (g * 8 + j)) & 1u) ? pe : 0.f;
            rs += p;
            afr[j] = f2b(p);
        }
        #pragma unroll
        for (int dt = 0; dt < 4; ++dt) {
            const bf16x8 bfr =
                *(const bf16x8*)(xbase + ((size_t)(dt * 64 + kk) << 9) + lane * 8);
            acc[dt] = __builtin_amdgcn_mfma_f32_16x16x32_bf16(afr, bfr, acc[dt], 0, 0, 0);
        }
    }

    // ---- partial row sums of this k-quarter (same value in all 4 g-copies) ----
    rs += __shfl_xor(rs, 16);
    rs += __shfl_xor(rs, 32);
    if (lane < 16) rs_lds[w * 16 + lane] = rs;

    // ---- C partials to LDS ----
    #pragma unroll
    for (int dt = 0; dt < 4; ++dt)
        #pragma unroll
        for (int reg = 0; reg < 4; ++reg)
            red[w][dt][g * 4 + reg][lr] = acc[dt][reg];
    __syncthreads();

    // ---- combine 4 k-quarters, normalize, store ----
    const int row = t >> 4;
    const int col = t & 15;
    const float nrm = 1.f / (rs_lds[row] + rs_lds[16 + row]
                           + rs_lds[32 + row] + rs_lds[48 + row]);
    #pragma unroll
    for (int dt = 0; dt < 4; ++dt) {
        const float v = red[0][dt][row][col] + red[1][dt][row][col]
                      + red[2][dt][row][col] + red[3][dt][row][col];
        out[(base + (size_t)(m0 + row)) * DOUT + dt * 16 + col] = v * nrm;
    }
}

extern "C" void kernel_launch(void* const* d_in, const int* in_sizes, int n_in,
                              void* d_out, int out_size, void* d_ws, size_t ws_size,
                              hipStream_t stream) {
    const float* x    = (const float*)d_in[0];
    const int*   adj  = (const int*)d_in[1];
    const float* W    = (const float*)d_in[2];
    const float* bvec = (const float*)d_in[3];
    const float* a    = (const float*)d_in[4];
    float* out = (float*)d_out;

    unsigned short* xpF = (unsigned short*)d_ws;          // 2 MB bf16 frag-ordered
    float* e_src = (float*)((char*)d_ws + (1 << 21));     // 64 KB
    float* e_dst = e_src + (size_t)BB * NN;               // 64 KB

    gat_xp_mfma<<<(BB * NN) / 32, 256, 0, stream>>>(x, W, bvec, a, xpF, e_src, e_dst);
    gat_attn_mfma<<<BB * (NN / 16), 256, 0, stream>>>(adj, xpF, e_src, e_dst, out);
}